// Round 3
// baseline (348.281 us; speedup 1.0000x reference)
//
#include <hip/hip_runtime.h>
#include <stdint.h>

typedef unsigned short u16;
typedef __bf16 bf16x8 __attribute__((ext_vector_type(8)));
typedef float f32x4 __attribute__((ext_vector_type(4)));

// x:  [16][256][64][64] fp32
// w:  [256][128][4][4]  fp32
// out:[16][128][128][128] fp32
// x_t  (ws): [16][66][66][256] bf16, spatially padded by 1 with zeros (NHWC)
// Aswz (ws): [cls 4][wm 2][u 32][i 4][lane 64][j 8] bf16 fragment-ordered weights
static const size_t XT_BYTES = (size_t)16 * 66 * 66 * 256 * 2; // 35,684,352
static const size_t WK_BYTES = (size_t)4 * 2 * 32 * 4 * 64 * 8 * 2; // 1,048,576

__device__ __forceinline__ u16 f2bf(float f) {
  unsigned u = __float_as_uint(f);
  unsigned r = (u + 0x7fff + ((u >> 16) & 1)) >> 16; // RNE
  return (u16)r;
}

// ---------------- prep: x fp32 NCHW -> bf16 padded NHWC (incl. borders) ----------------
// block: ih = bx (0..63), ci-half = by (0..1), n = bz
__global__ __launch_bounds__(256) void prep_x(const float* __restrict__ x,
                                              u16* __restrict__ xt) {
  __shared__ __align__(16) u16 shb[128 * 68];  // [ci_local][iw], pitch 68 u16
  __shared__ __align__(16) uint4 sh2[64 * 17]; // [iw][chunk], pitch 17 uint4
  const int t = threadIdx.x;
  const int ih = blockIdx.x, half = blockIdx.y, n = blockIdx.z;
  const int ci0 = half * 128;
  const uint4 z4 = make_uint4(0, 0, 0, 0);
  // phase a: coalesced float4 reads, bf16 convert, LDS write
#pragma unroll
  for (int it = 0; it < 8; ++it) {
    const int cil = it * 16 + (t >> 4);
    const int iw4 = t & 15;
    const float4 v =
        *(const float4*)&x[(((size_t)n * 256 + ci0 + cil) * 64 + ih) * 64 + iw4 * 4];
    ushort4 h;
    h.x = f2bf(v.x); h.y = f2bf(v.y); h.z = f2bf(v.z); h.w = f2bf(v.w);
    *(ushort4*)&shb[cil * 68 + iw4 * 4] = h;
  }
  __syncthreads();
  // phase b: transposed reads (2-way, free), pack uint4
  {
    const int iw = t & 63;
    const int cq = t >> 6;
#pragma unroll
    for (int j = 0; j < 4; ++j) {
      const int chunk = cq * 4 + j;
      u16 vals[8];
#pragma unroll
      for (int r = 0; r < 8; ++r) vals[r] = shb[(chunk * 8 + r) * 68 + iw];
      uint4 o;
      o.x = (unsigned)vals[0] | ((unsigned)vals[1] << 16);
      o.y = (unsigned)vals[2] | ((unsigned)vals[3] << 16);
      o.z = (unsigned)vals[4] | ((unsigned)vals[5] << 16);
      o.w = (unsigned)vals[6] | ((unsigned)vals[7] << 16);
      sh2[iw * 17 + chunk] = o;
    }
  }
  __syncthreads();
  // phase c: coalesced global writes (interior row ihp=ih+1, iwp 1..64)
  u16* dst = xt + (((size_t)n * 66 + ih + 1) * 66 + 1) * 256 + ci0;
#pragma unroll
  for (int j2 = 0; j2 < 4; ++j2) {
    const int idx = j2 * 256 + t;
    const int iw = idx >> 4, chunk = idx & 15;
    *(uint4*)&dst[(size_t)iw * 256 + chunk * 8] = sh2[iw * 17 + chunk];
  }
  // side borders iwp = 0, 65 of this row (our ci-half)
  if (t < 32) {
    const int iwp = (t >> 4) * 65;
    const int chunk = t & 15;
    *(uint4*)&xt[(((size_t)n * 66 + ih + 1) * 66 + iwp) * 256 + ci0 + chunk * 8] = z4;
  }
  // top/bottom border rows ihp = 0, 65 (our ci-half, all 66 pixels)
  if (ih == 0 || ih == 63) {
    const int ihp = (ih == 0) ? 0 : 65;
    u16* row = xt + (((size_t)n * 66 + ihp) * 66) * 256 + ci0;
#pragma unroll
    for (int jj = 0; jj < 5; ++jj) {
      int idx = jj * 256 + t;
      if (idx < 66 * 16) {
        int pix = idx >> 4, chunk = idx & 15;
        *(uint4*)&row[(size_t)pix * 256 + chunk * 8] = z4;
      }
    }
  }
}

// ---------------- prep: weights -> fragment-ordered bf16 A_swz ----------------
// flat id = ((((cls*2+wm)*32+u)*4+i)*64+lane)*8 + j
__global__ __launch_bounds__(256) void prep_w(const float* __restrict__ w,
                                              u16* __restrict__ aswz) {
  int id = blockIdx.x * 256 + threadIdx.x; // < 524288
  int j = id & 7;
  int lane = (id >> 3) & 63;
  int i = (id >> 9) & 3;
  int u = (id >> 11) & 31;
  int wm = (id >> 16) & 1;
  int cls = (id >> 17) & 3;
  int quad = lane >> 4, l15 = lane & 15;
  int k = u * 32 + quad * 8 + j;
  int ci = k & 255, tap = k >> 8;
  int co = wm * 64 + i * 16 + l15;
  int p = cls >> 1, q = cls & 1;
  int kh = 2 * (tap >> 1) + 1 - p;
  int kw = 2 * (tap & 1) + 1 - q;
  aswz[id] = f2bf(w[((ci * 128 + co) * 4 + kh) * 4 + kw]);
}

// ---------------- main: barrier-free register-direct implicit GEMM ----------------
// Per (n, cls): C[co][m*64+l] = sum_k A[co][k] * B[k][col]; k = tap*256 + ci.
// Block = 128 co x (2 m-rows x 64 l). Wave (wm, wn) = (co half, m-row).
__global__ __launch_bounds__(256, 3) void gemm_ct(const u16* __restrict__ xt,
                                                  const u16* __restrict__ aswz,
                                                  const float* __restrict__ bias,
                                                  float* __restrict__ out) {
  const int t = threadIdx.x;
  const int lane = t & 63;
  const int wv = t >> 6;
  const int wm = wv >> 1, wn = wv & 1;
  const int quad = lane >> 4, l15 = lane & 15;
  const int bx = blockIdx.x;  // 0..127 = cls*32 + mt (same mt -> same XCD for all cls)
  const int cls = bx >> 5, mt = bx & 31;
  const int n = blockIdx.y;
  const int p = cls >> 1, q = cls & 1;
  const int m = mt * 2 + wn; // this wave's m-row (0..63)

  // A base: frag (u,i) is 512 u16 apart; lane offset 8 u16
  const u16* Ab = aswz + ((size_t)(cls * 2 + wm) << 16) + lane * 8;
  // B bases per j at (tap=0): pixel (ihp = m+p+1, iwp = l+q+1), ci-chunk quad
  const u16* Bb[4];
#pragma unroll
  for (int j = 0; j < 4; ++j)
    Bb[j] = xt + (((size_t)n * 66 + (m + p + 1)) * 66 + (j * 16 + l15 + q + 1)) * 256 +
            quad * 8;

  f32x4 acc[4][4];
#pragma unroll
  for (int i = 0; i < 4; ++i)
#pragma unroll
    for (int j = 0; j < 4; ++j) acc[i][j] = (f32x4){0.f, 0.f, 0.f, 0.f};

  bf16x8 A0[4], B0[4], A1[4], B1[4];

#define LD(u, Af, Bf)                                                         \
  {                                                                           \
    const int tap_ = (u) >> 3, s_ = (u) & 7;                                  \
    const int boff_ = s_ * 32 - ((tap_ >> 1) * 66 + (tap_ & 1)) * 256;        \
    _Pragma("unroll") for (int i = 0; i < 4; ++i)                             \
        Af[i] = *(const bf16x8*)(Ab + (u) * 2048 + i * 512);                  \
    _Pragma("unroll") for (int j = 0; j < 4; ++j)                             \
        Bf[j] = *(const bf16x8*)(Bb[j] + boff_);                              \
  }
#define MM(Af, Bf)                                                            \
  {                                                                           \
    _Pragma("unroll") for (int i = 0; i < 4; ++i)                             \
        _Pragma("unroll") for (int j = 0; j < 4; ++j) acc[i][j] =             \
            __builtin_amdgcn_mfma_f32_16x16x32_bf16(Af[i], Bf[j], acc[i][j],  \
                                                    0, 0, 0);                 \
  }

  LD(0, A0, B0);
#pragma unroll
  for (int uu = 0; uu < 32; uu += 2) {
    LD(uu + 1, A1, B1);
    MM(A0, B0);
    if (uu + 2 < 32) LD(uu + 2, A0, B0);
    MM(A1, B1);
  }
#undef LD
#undef MM

  // epilogue: C/D layout col=lane&15, row=quad*4+reg
  const int oh = 2 * m + p;
#pragma unroll
  for (int i = 0; i < 4; ++i) {
#pragma unroll
    for (int j = 0; j < 4; ++j) {
      f32x4 v = acc[i][j];
      int l = j * 16 + l15;
      int ow = 2 * l + q;
#pragma unroll
      for (int r = 0; r < 4; ++r) {
        int co = wm * 64 + i * 16 + quad * 4 + r;
        out[(((size_t)n * 128 + co) * 128 + oh) * 128 + ow] = v[r] + bias[co];
      }
    }
  }
}

// ---------------- safety fallback (ws too small): direct fp32 ----------------
__global__ __launch_bounds__(256) void ct_fallback(const float* __restrict__ x,
                                                   const float* __restrict__ w,
                                                   const float* __restrict__ bias,
                                                   float* __restrict__ out) {
  size_t id = (size_t)blockIdx.x * 256 + threadIdx.x;
  if (id >= (size_t)16 * 128 * 128 * 128) return;
  int ow = (int)(id & 127), oh = (int)(id >> 7) & 127;
  int co = (int)(id >> 14) & 127, n = (int)(id >> 21);
  int pp = oh & 1, m = oh >> 1, qq = ow & 1, l = ow >> 1;
  float s = bias[co];
  for (int ci = 0; ci < 256; ++ci) {
    for (int dh = 0; dh < 2; ++dh) {
      int ih = m + pp - dh;
      if (ih < 0 || ih > 63) continue;
      int kh = 2 * dh + 1 - pp;
      for (int dw = 0; dw < 2; ++dw) {
        int iw = l + qq - dw;
        if (iw < 0 || iw > 63) continue;
        int kw = 2 * dw + 1 - qq;
        s += x[(((size_t)n * 256 + ci) * 64 + ih) * 64 + iw] *
             w[((ci * 128 + co) * 4 + kh) * 4 + kw];
      }
    }
  }
  out[id] = s;
}

extern "C" void kernel_launch(void* const* d_in, const int* in_sizes, int n_in,
                              void* d_out, int out_size, void* d_ws, size_t ws_size,
                              hipStream_t stream) {
  const float* x = (const float*)d_in[0];
  const float* w = (const float*)d_in[1];
  const float* bias = (const float*)d_in[2];
  float* out = (float*)d_out;
  if (ws_size >= XT_BYTES + WK_BYTES) {
    u16* xt = (u16*)d_ws;
    u16* aswz = (u16*)((char*)d_ws + XT_BYTES);
    hipLaunchKernelGGL(prep_w, dim3(2048), dim3(256), 0, stream, w, aswz);
    hipLaunchKernelGGL(prep_x, dim3(64, 2, 16), dim3(256), 0, stream, x, xt);
    hipLaunchKernelGGL(gemm_ct, dim3(128, 16), dim3(256), 0, stream, xt, aswz, bias, out);
  } else {
    hipLaunchKernelGGL(ct_fallback, dim3(131072), dim3(256), 0, stream, x, w, bias, out);
  }
}